// Round 4
// baseline (139.298 us; speedup 1.0000x reference)
//
#include <hip/hip_runtime.h>
#include <hip/hip_bf16.h>

// out[m, f] = sum_e cos(x[m, e] + theta[e & 7]) * W[f, e]
// M = 65536, N = K = 512.  bf16 MFMA GEMM, A = cos(x+theta) fused in staging.
//
// Structure: block = 32x512 output stripe (full N -> x read exactly once).
// Stage full 32x512 A-tile (bf16, XOR-swizzled) in 32 KB LDS, ONE barrier,
// then a fully-unrolled barrier-free 16-step K loop (K_STEP=32) with 2-deep
// register prefetch of B (bf16 W in d_ws, L2-resident) and 1-deep A ds_read
// prefetch. MFMA operands swapped so the epilogue is dense float4 NT stores.

typedef __attribute__((ext_vector_type(8))) short short8;   // 8 x bf16
typedef __attribute__((ext_vector_type(4))) float f32x4;    // MFMA acc frag

static constexpr int KD  = 512;
static constexpr int ND  = 512;
static constexpr int BM  = 32;
static constexpr int NKF = 16;           // K steps of 32

static __device__ __forceinline__ unsigned short f2bf(float f) {
    unsigned int b = __builtin_bit_cast(unsigned int, f);
    b += 0x7FFFu + ((b >> 16) & 1u);
    return (unsigned short)(b >> 16);
}

// cos via v_cos_f32: input in revolutions, explicit fract for range safety.
static __device__ __forceinline__ float fast_cos_rev(float rev) {
    float r = rev - __builtin_floorf(rev);
    float c;
    asm("v_cos_f32 %0, %1" : "=v"(c) : "v"(r));
    return c;
}

__global__ void cvt_w_kernel(const float* __restrict__ W,
                             unsigned short* __restrict__ Wb, int n4) {
    int i = blockIdx.x * blockDim.x + threadIdx.x;
    if (i < n4) {
        float4 v = reinterpret_cast<const float4*>(W)[i];
        ushort4 o;
        o.x = f2bf(v.x); o.y = f2bf(v.y); o.z = f2bf(v.z); o.w = f2bf(v.w);
        reinterpret_cast<ushort4*>(Wb)[i] = o;
    }
}

template <bool PRECVT>
__global__ __launch_bounds__(512, 4)
void fused_qgemm(const float* __restrict__ x, const float* __restrict__ theta,
                 const float* __restrict__ W, const unsigned short* __restrict__ Wb,
                 float* __restrict__ out) {
    __shared__ unsigned short Alds[BM * KD];   // 32 KB, row pitch 1024 B, swizzled

    const int tid  = threadIdx.x;
    const int lane = tid & 63;
    const int wave = tid >> 6;                 // 0..7 -> n0 = wave*64
    const int m0   = blockIdx.x * BM;
    const int n0   = wave * 64;

    const int frow = lane & 15;                // fragment row/col index
    const int fkg  = lane >> 4;                // k-group 0..3

    constexpr float INV2PI = 0.15915493667125702f;
    float thC[8];
#pragma unroll
    for (int j = 0; j < 8; ++j) thC[j] = theta[j] * INV2PI;

    // ---- B fragment base pointers (kf advances via immediate offset) ----
    const unsigned short* wp[4];
    const float* wpf[4];
#pragma unroll
    for (int jn = 0; jn < 4; ++jn) {
        const size_t nn = (size_t)(n0 + jn * 16 + frow) * KD + fkg * 8;
        wp[jn]  = PRECVT ? (Wb + nn) : (const unsigned short*)nullptr;
        wpf[jn] = W + nn;
    }

    auto loadB = [&](int kf, short8* dst) {
#pragma unroll
        for (int jn = 0; jn < 4; ++jn) {
            if (PRECVT) {
                dst[jn] = *reinterpret_cast<const short8*>(wp[jn] + kf * 32);
            } else {
                float4 w0 = *reinterpret_cast<const float4*>(wpf[jn] + kf * 32);
                float4 w1 = *reinterpret_cast<const float4*>(wpf[jn] + kf * 32 + 4);
                short8 t8;
                t8[0] = (short)f2bf(w0.x); t8[1] = (short)f2bf(w0.y);
                t8[2] = (short)f2bf(w0.z); t8[3] = (short)f2bf(w0.w);
                t8[4] = (short)f2bf(w1.x); t8[5] = (short)f2bf(w1.y);
                t8[6] = (short)f2bf(w1.z); t8[7] = (short)f2bf(w1.w);
                dst[jn] = t8;
            }
        }
    };

    short8 bb[3][4];
    f32x4  acc[2][4];
#pragma unroll
    for (int i = 0; i < 2; ++i)
#pragma unroll
        for (int j = 0; j < 4; ++j) acc[i][j] = (f32x4)(0.0f);

    // ---- stage A tile: 32 rows x 512 cols; issue all x loads first ----
    {
        const int srow = tid >> 4;             // 0..31
        const int sc0  = (tid & 15) * 8;       // 0..120
        const float* xp = x + (size_t)(m0 + srow) * KD + sc0;
        float4 xv[4][2];
#pragma unroll
        for (int c = 0; c < 4; ++c) {
            xv[c][0] = *reinterpret_cast<const float4*>(xp + c * 128);
            xv[c][1] = *reinterpret_cast<const float4*>(xp + c * 128 + 4);
        }
        // B prefetch for kf=0,1: independent of LDS, flies across the barrier
        loadB(0, bb[0]);
        loadB(1, bb[1]);

        char* lb = reinterpret_cast<char*>(&Alds[0]) + srow * 1024;
        const int swz = (srow & 7) << 4;
#pragma unroll
        for (int c = 0; c < 4; ++c) {
            float v[8];
            *reinterpret_cast<float4*>(&v[0]) = xv[c][0];
            *reinterpret_cast<float4*>(&v[4]) = xv[c][1];
            short8 pk;
#pragma unroll
            for (int j = 0; j < 8; ++j)    // (sc0 + c*128) % 8 == 0 -> theta idx j
                pk[j] = (short)f2bf(fast_cos_rev(__builtin_fmaf(v[j], INV2PI, thC[j])));
            *reinterpret_cast<short8*>(lb + (((sc0 + c * 128) * 2) ^ swz)) = pk;
        }
    }
    __syncthreads();

    auto loadA = [&](int kf, short8* dst) {
#pragma unroll
        for (int i = 0; i < 2; ++i) {
            const int row  = i * 16 + frow;
            const int byte = row * 1024 + (((kf * 32 + fkg * 8) * 2) ^ ((row & 7) << 4));
            dst[i] = *reinterpret_cast<const short8*>(
                reinterpret_cast<const char*>(&Alds[0]) + byte);
        }
    };

    short8 aa[2][2];
    loadA(0, aa[0]);

    // ---- barrier-free K loop, fully unrolled, 2-deep B / 1-deep A ----
#pragma unroll
    for (int kf = 0; kf < NKF; ++kf) {
        if (kf + 1 < NKF) loadA(kf + 1, aa[(kf + 1) & 1]);
        if (kf + 2 < NKF) loadB(kf + 2, bb[(kf + 2) % 3]);
#pragma unroll
        for (int i = 0; i < 2; ++i)
#pragma unroll
            for (int jn = 0; jn < 4; ++jn)
                acc[i][jn] = __builtin_amdgcn_mfma_f32_16x16x32_bf16(
                    bb[kf % 3][jn], aa[kf & 1][i], acc[i][jn], 0, 0, 0);
    }

    // ---- epilogue: swapped-operand D layout -> reg index runs along N ----
    // m = m0 + i*16 + frow (col=lane&15), n = n0 + jn*16 + fkg*4 + r
    float* op = out + (size_t)(m0 + frow) * ND + n0 + fkg * 4;
#pragma unroll
    for (int i = 0; i < 2; ++i)
#pragma unroll
        for (int jn = 0; jn < 4; ++jn)
            __builtin_nontemporal_store(acc[i][jn],
                reinterpret_cast<f32x4*>(op + (size_t)(i * 16) * ND + jn * 16));
}

extern "C" void kernel_launch(void* const* d_in, const int* in_sizes, int n_in,
                              void* d_out, int out_size, void* d_ws, size_t ws_size,
                              hipStream_t stream) {
    const float* x     = (const float*)d_in[0];
    const float* theta = (const float*)d_in[1];
    const float* W     = (const float*)d_in[2];
    float* out         = (float*)d_out;

    const int M      = in_sizes[0] / KD;       // 65536
    const int wElems = in_sizes[2];            // 512*512

    if (ws_size >= (size_t)wElems * sizeof(unsigned short)) {
        unsigned short* Wb = (unsigned short*)d_ws;
        cvt_w_kernel<<<(wElems / 4 + 255) / 256, 256, 0, stream>>>(W, Wb, wElems / 4);
        fused_qgemm<true><<<M / BM, 512, 0, stream>>>(x, theta, W, Wb, out);
    } else {
        fused_qgemm<false><<<M / BM, 512, 0, stream>>>(x, theta, W, nullptr, out);
    }
}

// Round 5
// 78.460 us; speedup vs baseline: 1.7754x; 1.7754x over previous
//
#include <hip/hip_runtime.h>
#include <hip/hip_bf16.h>

// out[m, f] = sum_e cos(x[m, e] + theta[e & 7]) * W[f, e]
// M = 65536, N = K = 512.  bf16 MFMA GEMM, A = cos(x+theta) fused in staging.
//
// Block = 32x512 output stripe (full N -> x read exactly once from HBM).
// A: full 32x512 bf16 tile in 32 KB LDS (XOR-swizzled), ONE barrier.
// B: W pre-packed in d_ws in MFMA-fragment-major order -> every fragment load
//    is one fully-coalesced 16B/lane dwordx4 (8 x 128B lines per wave).
// K loop: fully unrolled 16 steps, 2-deep B / 1-deep A register prefetch,
// sched_barrier(0) per step pins issue order -> counted vmcnt/lgkmcnt waits.

typedef __attribute__((ext_vector_type(8))) short short8;   // 8 x bf16
typedef __attribute__((ext_vector_type(4))) float f32x4;    // MFMA acc frag

static constexpr int KD  = 512;
static constexpr int ND  = 512;
static constexpr int BM  = 32;
static constexpr int NKF = 16;           // K steps of 32

static __device__ __forceinline__ unsigned short f2bf(float f) {
    unsigned int b = __builtin_bit_cast(unsigned int, f);
    b += 0x7FFFu + ((b >> 16) & 1u);
    return (unsigned short)(b >> 16);
}

// cos via v_cos_f32: input in revolutions, explicit fract for range safety.
static __device__ __forceinline__ float fast_cos_rev(float rev) {
    float r = rev - __builtin_floorf(rev);
    float c;
    asm("v_cos_f32 %0, %1" : "=v"(c) : "v"(r));
    return c;
}

// Pack W into MFMA-fragment-major bf16:
//   WbF[((n_blk*16 + kf)*64 + lane)*8 + j] =
//       bf16( W[n_blk*16 + (lane&15)][kf*32 + (lane>>4)*8 + j] )
__global__ void cvt_w_frag(const float* __restrict__ W,
                           unsigned short* __restrict__ WbF) {
    const int i    = blockIdx.x * 256 + threadIdx.x;  // 0..32767 fragments
    const int lane = i & 63;
    const int kf   = (i >> 6) & 15;
    const int nblk = i >> 10;                         // 0..31
    const int row  = nblk * 16 + (lane & 15);         // f index
    const int col  = kf * 32 + (lane >> 4) * 8;       // e index
    const float* p = W + (size_t)row * KD + col;
    float4 w0 = *reinterpret_cast<const float4*>(p);
    float4 w1 = *reinterpret_cast<const float4*>(p + 4);
    short8 t8;
    t8[0] = (short)f2bf(w0.x); t8[1] = (short)f2bf(w0.y);
    t8[2] = (short)f2bf(w0.z); t8[3] = (short)f2bf(w0.w);
    t8[4] = (short)f2bf(w1.x); t8[5] = (short)f2bf(w1.y);
    t8[6] = (short)f2bf(w1.z); t8[7] = (short)f2bf(w1.w);
    *reinterpret_cast<short8*>(WbF + (size_t)i * 8) = t8;
}

template <bool PRECVT>
__global__ __launch_bounds__(512, 4)
void fused_qgemm(const float* __restrict__ x, const float* __restrict__ theta,
                 const float* __restrict__ W, const unsigned short* __restrict__ WbF,
                 float* __restrict__ out) {
    __shared__ unsigned short Alds[BM * KD];   // 32 KB, row pitch 1024 B, swizzled

    const int tid  = threadIdx.x;
    const int lane = tid & 63;
    const int wave = tid >> 6;                 // 0..7 -> n0 = wave*64
    const int m0   = blockIdx.x * BM;
    const int n0   = wave * 64;

    const int frow = lane & 15;                // fragment row/col index
    const int fkg  = lane >> 4;                // k-group 0..3

    constexpr float INV2PI = 0.15915493667125702f;
    float thC[8];
#pragma unroll
    for (int j = 0; j < 8; ++j) thC[j] = theta[j] * INV2PI;

    // ---- B: fragment-major base (fully coalesced 16B/lane loads) ----
    const unsigned short* wbase =
        PRECVT ? (WbF + ((size_t)wave * 4096 + lane) * 8) : nullptr;
    const float* wpf[4];
#pragma unroll
    for (int jn = 0; jn < 4; ++jn)
        wpf[jn] = W + (size_t)(n0 + jn * 16 + frow) * KD + fkg * 8;

    auto loadB = [&](int kf, short8* dst) {
#pragma unroll
        for (int jn = 0; jn < 4; ++jn) {
            if (PRECVT) {
                dst[jn] = *reinterpret_cast<const short8*>(
                    wbase + (size_t)(jn * 16 + kf) * 512);
            } else {
                float4 w0 = *reinterpret_cast<const float4*>(wpf[jn] + kf * 32);
                float4 w1 = *reinterpret_cast<const float4*>(wpf[jn] + kf * 32 + 4);
                short8 t8;
                t8[0] = (short)f2bf(w0.x); t8[1] = (short)f2bf(w0.y);
                t8[2] = (short)f2bf(w0.z); t8[3] = (short)f2bf(w0.w);
                t8[4] = (short)f2bf(w1.x); t8[5] = (short)f2bf(w1.y);
                t8[6] = (short)f2bf(w1.z); t8[7] = (short)f2bf(w1.w);
                dst[jn] = t8;
            }
        }
    };

    short8 bb[3][4];
    f32x4  acc[2][4];
#pragma unroll
    for (int i = 0; i < 2; ++i)
#pragma unroll
        for (int j = 0; j < 4; ++j) acc[i][j] = (f32x4)(0.0f);

    // ---- stage A tile: 32 rows x 512 cols; x loads + B(0,1) fly together ----
    {
        const int srow = tid >> 4;             // 0..31
        const int sc0  = (tid & 15) * 8;       // 0..120
        const float* xp = x + (size_t)(m0 + srow) * KD + sc0;
        float4 xv[4][2];
#pragma unroll
        for (int c = 0; c < 4; ++c) {
            xv[c][0] = *reinterpret_cast<const float4*>(xp + c * 128);
            xv[c][1] = *reinterpret_cast<const float4*>(xp + c * 128 + 4);
        }
        loadB(0, bb[0]);
        loadB(1, bb[1]);

        char* lb = reinterpret_cast<char*>(&Alds[0]) + srow * 1024;
        const int swz = (srow & 7) << 4;
#pragma unroll
        for (int c = 0; c < 4; ++c) {
            float v[8];
            *reinterpret_cast<float4*>(&v[0]) = xv[c][0];
            *reinterpret_cast<float4*>(&v[4]) = xv[c][1];
            short8 pk;
#pragma unroll
            for (int j = 0; j < 8; ++j)    // (sc0 + c*128) % 8 == 0 -> theta idx j
                pk[j] = (short)f2bf(fast_cos_rev(__builtin_fmaf(v[j], INV2PI, thC[j])));
            *reinterpret_cast<short8*>(lb + (((sc0 + c * 128) * 2) ^ swz)) = pk;
        }
    }
    __syncthreads();

    auto loadA = [&](int kf, short8* dst) {
#pragma unroll
        for (int i = 0; i < 2; ++i) {
            const int row  = i * 16 + frow;
            const int byte = row * 1024 + (((kf * 32 + fkg * 8) * 2) ^ ((row & 7) << 4));
            dst[i] = *reinterpret_cast<const short8*>(
                reinterpret_cast<const char*>(&Alds[0]) + byte);
        }
    };

    short8 aa[2][2];
    loadA(0, aa[0]);

    // ---- K loop: issue loads first, pin with sched_barrier, then MFMA ----
#pragma unroll
    for (int kf = 0; kf < NKF; ++kf) {
        if (kf + 1 < NKF) loadA(kf + 1, aa[(kf + 1) & 1]);
        if (kf + 2 < NKF) loadB(kf + 2, bb[(kf + 2) % 3]);
        __builtin_amdgcn_sched_barrier(0);
#pragma unroll
        for (int i = 0; i < 2; ++i)
#pragma unroll
            for (int jn = 0; jn < 4; ++jn)
                acc[i][jn] = __builtin_amdgcn_mfma_f32_16x16x32_bf16(
                    bb[kf % 3][jn], aa[kf & 1][i], acc[i][jn], 0, 0, 0);
    }

    // ---- epilogue: m = m0 + i*16 + frow, n = n0 + jn*16 + fkg*4 + r ----
    float* op = out + (size_t)(m0 + frow) * ND + n0 + fkg * 4;
#pragma unroll
    for (int i = 0; i < 2; ++i)
#pragma unroll
        for (int jn = 0; jn < 4; ++jn)
            *reinterpret_cast<f32x4*>(op + (size_t)(i * 16) * ND + jn * 16) =
                acc[i][jn];
}

extern "C" void kernel_launch(void* const* d_in, const int* in_sizes, int n_in,
                              void* d_out, int out_size, void* d_ws, size_t ws_size,
                              hipStream_t stream) {
    const float* x     = (const float*)d_in[0];
    const float* theta = (const float*)d_in[1];
    const float* W     = (const float*)d_in[2];
    float* out         = (float*)d_out;

    const int M      = in_sizes[0] / KD;       // 65536
    const int wElems = in_sizes[2];            // 512*512

    if (ws_size >= (size_t)wElems * sizeof(unsigned short)) {
        unsigned short* WbF = (unsigned short*)d_ws;
        cvt_w_frag<<<wElems / 8 / 256, 256, 0, stream>>>(W, WbF);
        fused_qgemm<true><<<M / BM, 512, 0, stream>>>(x, theta, W, WbF, out);
    } else {
        fused_qgemm<false><<<M / BM, 512, 0, stream>>>(x, theta, W, nullptr, out);
    }
}